// Round 8
// baseline (54.611 us; speedup 1.0000x reference)
//
#include <hip/hip_runtime.h>
#include <math.h>

#define NPIX 1048576
#define HH 64
#define NO 3
#define NBLK 2048
#define ITER 8     // NBLK * 4 waves * ITER * 16 px = 1048576
#define NOUT4 786432             // NPIX*NO/4 float4s
#define K2C 2.8853900817779268f  // 2*log2(e)
#define NFRAG 18                 // per-lane uint4 fragments in fr / LDS

typedef float f32x4 __attribute__((ext_vector_type(4)));
typedef __bf16 bf16x8 __attribute__((ext_vector_type(8)));
typedef __bf16 bf16x2 __attribute__((ext_vector_type(2)));

union BF8 { __bf16 h[8]; bf16x8 v; uint4 u4; };
union PK2 { bf16x2 h; unsigned u; };
union F4U { float f[4]; uint4 u; f32x4 v; };

#define MFMA16(a, b, c) __builtin_amdgcn_mfma_f32_16x16x32_bf16((a), (b), (c), 0, 0, 0)

// k-slot -> physical h index permutation: lane (G,q) holds C rows {16m+4G+r}
// and owns B-frag k-slots {8G+j} (Bf0) and {32+8G+j} (Bf1). Bijection:
__device__ __forceinline__ int hsel(int k) {
    const int G = (k & 31) >> 3, j = k & 7;
    return ((k >= 32) ? 32 : 0) + ((j >= 4) ? 16 : 0) + 4 * G + (j & 3);
}

// 4 tanh (inputs pre-scaled by 2*log2e, bias folded) -> 2 packed bf16 dwords.
// tanh = 1 - 2/(exp2(t)+1); pairwise-combined rcp: 1/a,1/b from rcp(a*b).
// Overflow-safe: a*b -> inf => rcp -> 0 => fma(-2,0,1) = 1 (correct saturation;
// harmful pair-overflow needs one saturated t>115 AND one tiny t<13 => |pre|>40, ~7 sigma).
__device__ __forceinline__ void tanh4_pack(const f32x4 c, unsigned* lo, unsigned* hi) {
    const float a0 = __builtin_amdgcn_exp2f(c[0]) + 1.0f;
    const float a1 = __builtin_amdgcn_exp2f(c[1]) + 1.0f;
    const float a2 = __builtin_amdgcn_exp2f(c[2]) + 1.0f;
    const float a3 = __builtin_amdgcn_exp2f(c[3]) + 1.0f;
    const float r01 = __builtin_amdgcn_rcpf(a0 * a1);
    const float r23 = __builtin_amdgcn_rcpf(a2 * a3);
    const float t0 = fmaf(-2.0f, a1 * r01, 1.0f);
    const float t1 = fmaf(-2.0f, a0 * r01, 1.0f);
    const float t2 = fmaf(-2.0f, a3 * r23, 1.0f);
    const float t3 = fmaf(-2.0f, a2 * r23, 1.0f);
    PK2 L, H;
    L.h = bf16x2{(__bf16)t0, (__bf16)t1};
    H.h = bf16x2{(__bf16)t2, (__bf16)t3};
    *lo = L.u; *hi = H.u;
}

// ---- pre-pack, 4-wave parallel (layout per lane: 18 uint4) ----
// [0..3]=A1 (K2-scaled, bias k-aug), [4..7]=A2[s=0][m], [8..11]=A2[s=1][m]
// (K2-scaled, k-permuted), [12..13]=A3 (k-permuted), [14..17]=K2*b2 C-init slice
__global__ __launch_bounds__(256) void cppn_pack(
    const float* __restrict__ W1, const float* __restrict__ b1,
    const float* __restrict__ W2, const float* __restrict__ b2,
    const float* __restrict__ W3, const float* __restrict__ b3,
    uint4* __restrict__ fr)
{
    const int t = threadIdx.x, w = t >> 6, l = t & 63, g = l >> 4, q = l & 15;
    uint4* o = fr + l * NFRAG;

    if (w == 0) {
        #pragma unroll
        for (int m = 0; m < 4; ++m) {
            BF8 tt;
            #pragma unroll
            for (int j = 0; j < 8; ++j) {
                const int k = g * 8 + j;
                float v = 0.0f;
                if (k < 4) v = W1[k * HH + m * 16 + q];
                else if (k == 4) v = b1[m * 16 + q];
                tt.h[j] = (__bf16)(K2C * v);
            }
            o[m] = tt.u4;
        }
    } else if (w == 1 || w == 2) {
        const int s = w - 1;
        #pragma unroll
        for (int m = 0; m < 4; ++m) {
            BF8 tt;
            #pragma unroll
            for (int j = 0; j < 8; ++j)
                tt.h[j] = (__bf16)(K2C * W2[hsel(s * 32 + g * 8 + j) * HH + m * 16 + q]);
            o[4 + s * 4 + m] = tt.u4;
        }
    } else {
        #pragma unroll
        for (int s = 0; s < 2; ++s) {
            BF8 tt;
            #pragma unroll
            for (int j = 0; j < 8; ++j)
                tt.h[j] = (q < NO) ? (__bf16)W3[hsel(s * 32 + g * 8 + j) * NO + q] : (__bf16)0.0f;
            o[12 + s] = tt.u4;
        }
        #pragma unroll
        for (int m = 0; m < 4; ++m) {
            F4U tt;
            #pragma unroll
            for (int r = 0; r < 4; ++r) tt.f[r] = K2C * b2[m * 16 + g * 4 + r];
            o[14 + m] = tt.u;
        }
    }
}

__global__ __launch_bounds__(256) void cppn_main(
    const float* __restrict__ x,
    const float* __restrict__ b3,
    const uint4* __restrict__ fr,
    float* __restrict__ out,
    float* __restrict__ pmin, float* __restrict__ pmax)
{
    // weights live in LDS, not persistent registers: [frag][lane] 18 KB
    __shared__ uint4 sfr[NFRAG * 64];
    __shared__ float rmin[4], rmax[4];

    const int t = threadIdx.x;
    const int w = t >> 6;
    const int l = t & 63;
    const int g = l >> 4;
    const int q = l & 15;

    // one-time fill from global fr (fr[i] = fr[lane*18 + frag]; coalesced reads)
    for (int i = t; i < NFRAG * 64; i += 256)
        sfr[(i % NFRAG) * 64 + (i / NFRAG)] = fr[i];
    __syncthreads();

    const float b30 = b3[0], b31 = b3[1], b32 = b3[2];
    const f32x4 z = {0.0f, 0.0f, 0.0f, 0.0f};
    float vmin = INFINITY, vmax = -INFINITY;

    const int pbase = ((blockIdx.x * 4 + w) * ITER) * 16 + q;  // pixel index, it steps +16
    const float4* x4 = reinterpret_cast<const float4*>(x);
    float4 cur = x4[pbase];

    const char* const sb = (const char*)sfr;
    int slo = l * 16;  // per-lane LDS byte offset; perturbed per-iter to defeat LICM

    for (int it = 0; it < ITER; ++it) {
        // make the LDS base "unknown" each iteration so frag reads stay in-loop
        asm volatile("" : "+v"(slo));
        const char* sp = sb + slo;

        // prefetch next iteration's x before the long compute body
        const int itn = (it + 1 < ITER) ? it + 1 : it;
        const float4 nxt = x4[pbase + itn * 16];

        // B1 frag: xaug^T[k][px]; only g==0 lanes carry {x0..x3, 1}
        BF8 bx;
        bx.u4 = uint4{0, 0, 0, 0};
        if (g == 0) {
            PK2 p01, p23;
            p01.h = bf16x2{(__bf16)cur.x, (__bf16)cur.y};
            p23.h = bf16x2{(__bf16)cur.z, (__bf16)cur.w};
            bx.u4.x = p01.u;
            bx.u4.y = p23.u;
            bx.u4.z = 0x3F80u;  // {1.0bf16, 0} bias lane k=4
        }

        // ---- layer 1 (A1 from LDS; frags transient) ----
        f32x4 c1[4];
        #pragma unroll
        for (int m = 0; m < 4; ++m) {
            BF8 a; a.u4 = *(const uint4*)(sp + m * 1024);
            c1[m] = MFMA16(a.v, bx.v, z);
        }

        unsigned pkx[4], pky[4];
        #pragma unroll
        for (int m = 0; m < 4; ++m) tanh4_pack(c1[m], &pkx[m], &pky[m]);
        BF8 Bf0, Bf1;
        Bf0.u4 = uint4{pkx[0], pky[0], pkx[1], pky[1]};
        Bf1.u4 = uint4{pkx[2], pky[2], pkx[3], pky[3]};

        __builtin_amdgcn_sched_barrier(0);

        // ---- layer 2a (A2[0] + Ci2 from LDS; bias via C-init) ----
        f32x4 c2[4];
        #pragma unroll
        for (int m = 0; m < 4; ++m) {
            BF8 a; a.u4 = *(const uint4*)(sp + (4 + m) * 1024);
            F4U ci; ci.u = *(const uint4*)(sp + (14 + m) * 1024);
            c2[m] = MFMA16(a.v, Bf0.v, ci.v);
        }
        __builtin_amdgcn_sched_barrier(0);
        // ---- layer 2b (A2[1] from LDS) ----
        #pragma unroll
        for (int m = 0; m < 4; ++m) {
            BF8 a; a.u4 = *(const uint4*)(sp + (8 + m) * 1024);
            c2[m] = MFMA16(a.v, Bf1.v, c2[m]);
        }

        #pragma unroll
        for (int m = 0; m < 4; ++m) tanh4_pack(c2[m], &pkx[m], &pky[m]);
        BF8 Bg0, Bg1;
        Bg0.u4 = uint4{pkx[0], pky[0], pkx[1], pky[1]};
        Bg1.u4 = uint4{pkx[2], pky[2], pkx[3], pky[3]};

        __builtin_amdgcn_sched_barrier(0);

        // ---- layer 3 (A3 from LDS) ----
        BF8 a30, a31;
        a30.u4 = *(const uint4*)(sp + 12 * 1024);
        a31.u4 = *(const uint4*)(sp + 13 * 1024);
        f32x4 c3 = MFMA16(a30.v, Bg0.v, z);
        c3 = MFMA16(a31.v, Bg1.v, c3);

        if (g == 0) {
            const int pxg = pbase + it * 16;
            const float o0 = c3[0] + b30;
            const float o1 = c3[1] + b31;
            const float o2 = c3[2] + b32;
            out[0 * NPIX + pxg] = o0;
            out[1 * NPIX + pxg] = o1;
            out[2 * NPIX + pxg] = o2;
            vmin = fminf(vmin, fminf(fminf(o0, o1), o2));
            vmax = fmaxf(vmax, fmaxf(fmaxf(o0, o1), o2));
        }
        cur = nxt;
    }

    // per-block min/max -> partials (no global atomics)
    #pragma unroll
    for (int off = 32; off > 0; off >>= 1) {
        vmin = fminf(vmin, __shfl_down(vmin, off));
        vmax = fmaxf(vmax, __shfl_down(vmax, off));
    }
    if (l == 0) { rmin[w] = vmin; rmax[w] = vmax; }
    __syncthreads();
    if (t == 0) {
        pmin[blockIdx.x] = fminf(fminf(rmin[0], rmin[1]), fminf(rmin[2], rmin[3]));
        pmax[blockIdx.x] = fmaxf(fmaxf(rmax[0], rmax[1]), fmaxf(rmax[2], rmax[3]));
    }
}

// fused reduce+norm: each block redundantly folds the 2048 partials (L2-hit),
// then normalizes its own float4 slice. Exact (min/max order-independent).
__global__ __launch_bounds__(256) void cppn_normred(
    float4* __restrict__ out,
    const float* __restrict__ pmin, const float* __restrict__ pmax)
{
    __shared__ float rmin[4], rmax[4];
    const int t = threadIdx.x, w = t >> 6, l = t & 63;
    float mn = INFINITY, mx = -INFINITY;
    #pragma unroll
    for (int i = 0; i < NBLK / 256; ++i) {
        mn = fminf(mn, pmin[i * 256 + t]);
        mx = fmaxf(mx, pmax[i * 256 + t]);
    }
    #pragma unroll
    for (int off = 32; off > 0; off >>= 1) {
        mn = fminf(mn, __shfl_down(mn, off));
        mx = fmaxf(mx, __shfl_down(mx, off));
    }
    if (l == 0) { rmin[w] = mn; rmax[w] = mx; }
    __syncthreads();
    mn = fminf(fminf(rmin[0], rmin[1]), fminf(rmin[2], rmin[3]));
    mx = fmaxf(fmaxf(rmax[0], rmax[1]), fmaxf(rmax[2], rmax[3]));
    const float inv = __fdividef(1.0f, mx - mn);

    const int i = blockIdx.x * 256 + t;
    float4 v = out[i];
    v.x = fminf(fmaxf((v.x - mn) * inv, 0.0f), 1.0f);
    v.y = fminf(fmaxf((v.y - mn) * inv, 0.0f), 1.0f);
    v.z = fminf(fmaxf((v.z - mn) * inv, 0.0f), 1.0f);
    v.w = fminf(fmaxf((v.w - mn) * inv, 0.0f), 1.0f);
    out[i] = v;
}

extern "C" void kernel_launch(void* const* d_in, const int* in_sizes, int n_in,
                              void* d_out, int out_size, void* d_ws, size_t ws_size,
                              hipStream_t stream) {
    const float* x  = (const float*)d_in[0];
    const float* W1 = (const float*)d_in[1];
    const float* b1 = (const float*)d_in[2];
    const float* W2 = (const float*)d_in[3];
    const float* b2 = (const float*)d_in[4];
    const float* W3 = (const float*)d_in[5];
    const float* b3 = (const float*)d_in[6];
    float* out = (float*)d_out;

    float* pmin = (float*)((char*)d_ws + 1024);          // 2048 floats
    float* pmax = (float*)((char*)d_ws + 1024 + 8192);   // 2048 floats
    uint4* fr   = (uint4*)((char*)d_ws + 32768);         // 64 lanes * 18 uint4 = 18 KB

    cppn_pack<<<1, 256, 0, stream>>>(W1, b1, W2, b2, W3, b3, fr);
    cppn_main<<<NBLK, 256, 0, stream>>>(x, b3, fr, out, pmin, pmax);
    cppn_normred<<<NOUT4 / 256, 256, 0, stream>>>((float4*)out, pmin, pmax);
}

// Round 11
// 52.164 us; speedup vs baseline: 1.0469x; 1.0469x over previous
//
#include <hip/hip_runtime.h>
#include <math.h>

#define NPIX 1048576
#define HH 64
#define NO 3
#define NBLK 2048
#define ITER 4     // NBLK * 4 waves * ITER * 32 px = 1048576
#define NOUT4 786432             // NPIX*NO/4 float4s
#define K2C 2.8853900817779268f  // 2*log2(e)
#define NFRAG 18                 // per-lane uint4 fragments in fr / LDS

typedef float f32x4 __attribute__((ext_vector_type(4)));
typedef __bf16 bf16x8 __attribute__((ext_vector_type(8)));
typedef __bf16 bf16x2 __attribute__((ext_vector_type(2)));

union BF8 { __bf16 h[8]; bf16x8 v; uint4 u4; };
union PK2 { bf16x2 h; unsigned u; };
union F4U { float f[4]; uint4 u; f32x4 v; };

#define MFMA16(a, b, c) __builtin_amdgcn_mfma_f32_16x16x32_bf16((a), (b), (c), 0, 0, 0)

// k-slot -> physical h index permutation: lane (G,q) holds C rows {16m+4G+r}
// and owns B-frag k-slots {8G+j} (Bf0) and {32+8G+j} (Bf1). Bijection:
__device__ __forceinline__ int hsel(int k) {
    const int G = (k & 31) >> 3, j = k & 7;
    return ((k >= 32) ? 32 : 0) + ((j >= 4) ? 16 : 0) + 4 * G + (j & 3);
}

// 4 tanh (inputs pre-scaled by 2*log2e, bias folded) -> 2 packed bf16 dwords.
// tanh = 1 - 2/(exp2(t)+1); pairwise-combined rcp: 1/a,1/b from rcp(a*b).
// Overflow-safe: a*b -> inf => rcp -> 0 => fma(-2,0,1) = 1 (correct saturation).
__device__ __forceinline__ void tanh4_pack(const f32x4 c, unsigned* lo, unsigned* hi) {
    const float a0 = __builtin_amdgcn_exp2f(c[0]) + 1.0f;
    const float a1 = __builtin_amdgcn_exp2f(c[1]) + 1.0f;
    const float a2 = __builtin_amdgcn_exp2f(c[2]) + 1.0f;
    const float a3 = __builtin_amdgcn_exp2f(c[3]) + 1.0f;
    const float r01 = __builtin_amdgcn_rcpf(a0 * a1);
    const float r23 = __builtin_amdgcn_rcpf(a2 * a3);
    const float t0 = fmaf(-2.0f, a1 * r01, 1.0f);
    const float t1 = fmaf(-2.0f, a0 * r01, 1.0f);
    const float t2 = fmaf(-2.0f, a3 * r23, 1.0f);
    const float t3 = fmaf(-2.0f, a2 * r23, 1.0f);
    PK2 L, H;
    L.h = bf16x2{(__bf16)t0, (__bf16)t1};
    H.h = bf16x2{(__bf16)t2, (__bf16)t3};
    *lo = L.u; *hi = H.u;
}

// ---- pre-pack, 4-wave parallel (layout per lane: 18 uint4) ----
// [0..3]=A1 (K2-scaled, bias k-aug), [4..7]=A2[s=0][m], [8..11]=A2[s=1][m]
// (K2-scaled, k-permuted), [12..13]=A3 (k-permuted), [14..17]=K2*b2 C-init slice
__global__ __launch_bounds__(256) void cppn_pack(
    const float* __restrict__ W1, const float* __restrict__ b1,
    const float* __restrict__ W2, const float* __restrict__ b2,
    const float* __restrict__ W3, const float* __restrict__ b3,
    uint4* __restrict__ fr)
{
    const int t = threadIdx.x, w = t >> 6, l = t & 63, g = l >> 4, q = l & 15;
    uint4* o = fr + l * NFRAG;

    if (w == 0) {
        #pragma unroll
        for (int m = 0; m < 4; ++m) {
            BF8 tt;
            #pragma unroll
            for (int j = 0; j < 8; ++j) {
                const int k = g * 8 + j;
                float v = 0.0f;
                if (k < 4) v = W1[k * HH + m * 16 + q];
                else if (k == 4) v = b1[m * 16 + q];
                tt.h[j] = (__bf16)(K2C * v);
            }
            o[m] = tt.u4;
        }
    } else if (w == 1 || w == 2) {
        const int s = w - 1;
        #pragma unroll
        for (int m = 0; m < 4; ++m) {
            BF8 tt;
            #pragma unroll
            for (int j = 0; j < 8; ++j)
                tt.h[j] = (__bf16)(K2C * W2[hsel(s * 32 + g * 8 + j) * HH + m * 16 + q]);
            o[4 + s * 4 + m] = tt.u4;
        }
    } else {
        #pragma unroll
        for (int s = 0; s < 2; ++s) {
            BF8 tt;
            #pragma unroll
            for (int j = 0; j < 8; ++j)
                tt.h[j] = (q < NO) ? (__bf16)W3[hsel(s * 32 + g * 8 + j) * NO + q] : (__bf16)0.0f;
            o[12 + s] = tt.u4;
        }
        #pragma unroll
        for (int m = 0; m < 4; ++m) {
            F4U tt;
            #pragma unroll
            for (int r = 0; r < 4; ++r) tt.f[r] = K2C * b2[m * 16 + g * 4 + r];
            o[14 + m] = tt.u;
        }
    }
}

__device__ __forceinline__ void make_bx(const float4 xv, int g, BF8* bx) {
    bx->u4 = uint4{0, 0, 0, 0};
    if (g == 0) {
        PK2 p01, p23;
        p01.h = bf16x2{(__bf16)xv.x, (__bf16)xv.y};
        p23.h = bf16x2{(__bf16)xv.z, (__bf16)xv.w};
        bx->u4.x = p01.u;
        bx->u4.y = p23.u;
        bx->u4.z = 0x3F80u;  // {1.0bf16, 0} bias lane k=4
    }
}

__global__ __launch_bounds__(256) void cppn_main(
    const float* __restrict__ x,
    const float* __restrict__ b3,
    const uint4* __restrict__ fr,
    float* __restrict__ out,
    float* __restrict__ pmin, float* __restrict__ pmax)
{
    // weights live in LDS, not persistent registers: [frag][lane] 18 KB
    __shared__ uint4 sfr[NFRAG * 64];
    __shared__ float rmin[4], rmax[4];

    const int t = threadIdx.x;
    const int w = t >> 6;
    const int l = t & 63;
    const int g = l >> 4;
    const int q = l & 15;

    // one-time fill from global fr (coalesced)
    for (int i = t; i < NFRAG * 64; i += 256)
        sfr[(i % NFRAG) * 64 + (i / NFRAG)] = fr[i];
    __syncthreads();

    const float b30 = b3[0], b31 = b3[1], b32 = b3[2];
    const f32x4 z = {0.0f, 0.0f, 0.0f, 0.0f};
    float vmin = INFINITY, vmax = -INFINITY;

    // each wave owns ITER bodies of 32 px: stream P = [pbase+it*32 .. +15], Q = [+16 .. +31]
    const int pbase = ((blockIdx.x * 4 + w) * ITER) * 32 + q;
    const float4* x4 = reinterpret_cast<const float4*>(x);
    float4 curP = x4[pbase];
    float4 curQ = x4[pbase + 16];

    const char* const sb = (const char*)sfr;
    int slo = l * 16;  // per-lane LDS byte offset; perturbed per-iter to defeat LICM

    for (int it = 0; it < ITER; ++it) {
        asm volatile("" : "+v"(slo));
        const char* sp = sb + slo;

        // prefetch next body's x before the long compute
        const int nofs = (it + 1 < ITER) ? (it + 1) * 32 : it * 32;
        const float4 nxtP = x4[pbase + nofs];
        const float4 nxtQ = x4[pbase + nofs + 16];

        BF8 bxP, bxQ;
        make_bx(curP, g, &bxP);
        make_bx(curQ, g, &bxQ);

        // ---- layer 1: shared A-read, paired MFMA ----
        f32x4 c1P[4], c1Q[4];
        #pragma unroll
        for (int m = 0; m < 4; ++m) {
            BF8 a; a.u4 = *(const uint4*)(sp + m * 1024);
            c1P[m] = MFMA16(a.v, bxP.v, z);
            c1Q[m] = MFMA16(a.v, bxQ.v, z);
        }

        unsigned pPx[4], pPy[4], pQx[4], pQy[4];
        #pragma unroll
        for (int m = 0; m < 4; ++m) {
            tanh4_pack(c1P[m], &pPx[m], &pPy[m]);
            tanh4_pack(c1Q[m], &pQx[m], &pQy[m]);
        }
        BF8 BfP0, BfP1, BfQ0, BfQ1;
        BfP0.u4 = uint4{pPx[0], pPy[0], pPx[1], pPy[1]};
        BfP1.u4 = uint4{pPx[2], pPy[2], pPx[3], pPy[3]};
        BfQ0.u4 = uint4{pQx[0], pQy[0], pQx[1], pQy[1]};
        BfQ1.u4 = uint4{pQx[2], pQy[2], pQx[3], pQy[3]};

        // ---- layer 2: shared A/Ci reads, paired MFMA (bias via C-init) ----
        f32x4 c2P[4], c2Q[4];
        #pragma unroll
        for (int m = 0; m < 4; ++m) {
            BF8 a; a.u4 = *(const uint4*)(sp + (4 + m) * 1024);
            F4U ci; ci.u = *(const uint4*)(sp + (14 + m) * 1024);
            c2P[m] = MFMA16(a.v, BfP0.v, ci.v);
            c2Q[m] = MFMA16(a.v, BfQ0.v, ci.v);
        }
        #pragma unroll
        for (int m = 0; m < 4; ++m) {
            BF8 a; a.u4 = *(const uint4*)(sp + (8 + m) * 1024);
            c2P[m] = MFMA16(a.v, BfP1.v, c2P[m]);
            c2Q[m] = MFMA16(a.v, BfQ1.v, c2Q[m]);
        }

        #pragma unroll
        for (int m = 0; m < 4; ++m) {
            tanh4_pack(c2P[m], &pPx[m], &pPy[m]);
            tanh4_pack(c2Q[m], &pQx[m], &pQy[m]);
        }
        BF8 BgP0, BgP1, BgQ0, BgQ1;
        BgP0.u4 = uint4{pPx[0], pPy[0], pPx[1], pPy[1]};
        BgP1.u4 = uint4{pPx[2], pPy[2], pPx[3], pPy[3]};
        BgQ0.u4 = uint4{pQx[0], pQy[0], pQx[1], pQy[1]};
        BgQ1.u4 = uint4{pQx[2], pQy[2], pQx[3], pQy[3]};

        // ---- layer 3: shared A-read, paired ----
        BF8 a30, a31;
        a30.u4 = *(const uint4*)(sp + 12 * 1024);
        a31.u4 = *(const uint4*)(sp + 13 * 1024);
        f32x4 c3P = MFMA16(a30.v, BgP0.v, z);
        f32x4 c3Q = MFMA16(a30.v, BgQ0.v, z);
        c3P = MFMA16(a31.v, BgP1.v, c3P);
        c3Q = MFMA16(a31.v, BgQ1.v, c3Q);

        if (g == 0) {
            const int pxg = pbase + it * 32;
            const float o0 = c3P[0] + b30, o1 = c3P[1] + b31, o2 = c3P[2] + b32;
            const float u0 = c3Q[0] + b30, u1 = c3Q[1] + b31, u2 = c3Q[2] + b32;
            out[0 * NPIX + pxg] = o0;
            out[1 * NPIX + pxg] = o1;
            out[2 * NPIX + pxg] = o2;
            out[0 * NPIX + pxg + 16] = u0;
            out[1 * NPIX + pxg + 16] = u1;
            out[2 * NPIX + pxg + 16] = u2;
            vmin = fminf(vmin, fminf(fminf(fminf(o0, o1), fminf(o2, u0)), fminf(u1, u2)));
            vmax = fmaxf(vmax, fmaxf(fmaxf(fmaxf(o0, o1), fmaxf(o2, u0)), fmaxf(u1, u2)));
        }
        curP = nxtP;
        curQ = nxtQ;
    }

    // per-block min/max -> partials (no global atomics)
    #pragma unroll
    for (int off = 32; off > 0; off >>= 1) {
        vmin = fminf(vmin, __shfl_down(vmin, off));
        vmax = fmaxf(vmax, __shfl_down(vmax, off));
    }
    if (l == 0) { rmin[w] = vmin; rmax[w] = vmax; }
    __syncthreads();
    if (t == 0) {
        pmin[blockIdx.x] = fminf(fminf(rmin[0], rmin[1]), fminf(rmin[2], rmin[3]));
        pmax[blockIdx.x] = fmaxf(fmaxf(rmax[0], rmax[1]), fmaxf(rmax[2], rmax[3]));
    }
}

// fused reduce+norm: each block redundantly folds the 2048 partials (L2-hit),
// then normalizes its own float4 slice. Exact (min/max order-independent).
__global__ __launch_bounds__(256) void cppn_normred(
    float4* __restrict__ out,
    const float* __restrict__ pmin, const float* __restrict__ pmax)
{
    __shared__ float rmin[4], rmax[4];
    const int t = threadIdx.x, w = t >> 6, l = t & 63;
    float mn = INFINITY, mx = -INFINITY;
    #pragma unroll
    for (int i = 0; i < NBLK / 256; ++i) {
        mn = fminf(mn, pmin[i * 256 + t]);
        mx = fmaxf(mx, pmax[i * 256 + t]);
    }
    #pragma unroll
    for (int off = 32; off > 0; off >>= 1) {
        mn = fminf(mn, __shfl_down(mn, off));
        mx = fmaxf(mx, __shfl_down(mx, off));
    }
    if (l == 0) { rmin[w] = mn; rmax[w] = mx; }
    __syncthreads();
    mn = fminf(fminf(rmin[0], rmin[1]), fminf(rmin[2], rmin[3]));
    mx = fmaxf(fmaxf(rmax[0], rmax[1]), fmaxf(rmax[2], rmax[3]));
    const float inv = __fdividef(1.0f, mx - mn);

    const int i = blockIdx.x * 256 + t;
    float4 v = out[i];
    v.x = fminf(fmaxf((v.x - mn) * inv, 0.0f), 1.0f);
    v.y = fminf(fmaxf((v.y - mn) * inv, 0.0f), 1.0f);
    v.z = fminf(fmaxf((v.z - mn) * inv, 0.0f), 1.0f);
    v.w = fminf(fmaxf((v.w - mn) * inv, 0.0f), 1.0f);
    out[i] = v;
}

extern "C" void kernel_launch(void* const* d_in, const int* in_sizes, int n_in,
                              void* d_out, int out_size, void* d_ws, size_t ws_size,
                              hipStream_t stream) {
    const float* x  = (const float*)d_in[0];
    const float* W1 = (const float*)d_in[1];
    const float* b1 = (const float*)d_in[2];
    const float* W2 = (const float*)d_in[3];
    const float* b2 = (const float*)d_in[4];
    const float* W3 = (const float*)d_in[5];
    const float* b3 = (const float*)d_in[6];
    float* out = (float*)d_out;

    float* pmin = (float*)((char*)d_ws + 1024);          // 2048 floats
    float* pmax = (float*)((char*)d_ws + 1024 + 8192);   // 2048 floats
    uint4* fr   = (uint4*)((char*)d_ws + 32768);         // 64 lanes * 18 uint4 = 18 KB

    cppn_pack<<<1, 256, 0, stream>>>(W1, b1, W2, b2, W3, b3, fr);
    cppn_main<<<NBLK, 256, 0, stream>>>(x, b3, fr, out, pmin, pmax);
    cppn_normred<<<NOUT4 / 256, 256, 0, stream>>>((float4*)out, pmin, pmax);
}

// Round 12
// 51.258 us; speedup vs baseline: 1.0654x; 1.0177x over previous
//
#include <hip/hip_runtime.h>
#include <math.h>

#define NPIX 1048576
#define HH 64
#define NO 3
#define NBLK 2048
#define ITER 8     // NBLK * 4 waves * ITER * 16 px = 1048576
#define NOUT4 786432             // NPIX*NO/4 float4s
#define K2C 2.8853900817779268f  // 2*log2(e)
#define NFRAG 18                 // per-lane uint4 fragments in fr

typedef float f32x4 __attribute__((ext_vector_type(4)));
typedef __bf16 bf16x8 __attribute__((ext_vector_type(8)));
typedef __bf16 bf16x2 __attribute__((ext_vector_type(2)));

union BF8 { __bf16 h[8]; bf16x8 v; uint4 u4; };
union PK2 { bf16x2 h; unsigned u; };
union F4U { float f[4]; uint4 u; f32x4 v; };

#define MFMA16(a, b, c) __builtin_amdgcn_mfma_f32_16x16x32_bf16((a), (b), (c), 0, 0, 0)

// k-slot -> physical h index permutation: lane (G,q) holds C rows {16m+4G+r}
// and owns B-frag k-slots {8G+j} (Bf0) and {32+8G+j} (Bf1). Bijection:
__device__ __forceinline__ int hsel(int k) {
    const int G = (k & 31) >> 3, j = k & 7;
    return ((k >= 32) ? 32 : 0) + ((j >= 4) ? 16 : 0) + 4 * G + (j & 3);
}

// sigmoid-reciprocal pack: r = 1/(exp2(t)+1), t pre-scaled by 2*log2e with bias
// folded. tanh(x) = 1 - 2r is ABSORBED INTO THE NEXT LAYER: W' = -2W,
// bias' = bias + W.1 (column sums, folded at pack time). Only exp2+add+rcp+cvt
// remain here. Overflow-safe: exp2->inf => rcp->0 => downstream h=1. 
__device__ __forceinline__ void rcp4_pack(const f32x4 c, unsigned* lo, unsigned* hi) {
    const float r0 = __builtin_amdgcn_rcpf(__builtin_amdgcn_exp2f(c[0]) + 1.0f);
    const float r1 = __builtin_amdgcn_rcpf(__builtin_amdgcn_exp2f(c[1]) + 1.0f);
    const float r2 = __builtin_amdgcn_rcpf(__builtin_amdgcn_exp2f(c[2]) + 1.0f);
    const float r3 = __builtin_amdgcn_rcpf(__builtin_amdgcn_exp2f(c[3]) + 1.0f);
    PK2 L, H;
    L.h = bf16x2{(__bf16)r0, (__bf16)r1};
    H.h = bf16x2{(__bf16)r2, (__bf16)r3};
    *lo = L.u; *hi = H.u;
}

// ---- pre-pack, 4-wave parallel (layout per lane: 18 uint4 + 1 shared) ----
// [0..3]=A1 (K2-scaled, bias k-aug), [4..11]=A2' = -2*K2*W2 (k-permuted),
// [12..13]=A3' = -2*W3 (k-permuted), [14..17]=Ci2' = K2*(b2 + colsum(W2)).
// fr[NFRAG*64] = b3' = b3 + colsum(W3).
__global__ __launch_bounds__(256) void cppn_pack(
    const float* __restrict__ W1, const float* __restrict__ b1,
    const float* __restrict__ W2, const float* __restrict__ b2,
    const float* __restrict__ W3, const float* __restrict__ b3,
    uint4* __restrict__ fr)
{
    __shared__ float cs2p[4][HH];  // partial column sums of W2
    __shared__ float cs3p[4][NO];  // partial column sums of W3
    const int t = threadIdx.x, w = t >> 6, l = t & 63, g = l >> 4, q = l & 15;

    // cooperative column sums: thread t sums 16 rows of column (t&63)
    {
        const int col = t & 63, part = t >> 6;
        float s = 0.0f;
        #pragma unroll
        for (int r = 0; r < 16; ++r) s += W2[(part * 16 + r) * HH + col];
        cs2p[part][col] = s;
    }
    if (t < 12) {
        const int o = t % 3, part = t / 3;
        float s = 0.0f;
        #pragma unroll
        for (int r = 0; r < 16; ++r) s += W3[(part * 16 + r) * NO + o];
        cs3p[part][o] = s;
    }
    __syncthreads();

    uint4* o = fr + l * NFRAG;

    if (w == 0) {
        // L1: A[row=h][k] = K2 * W1aug[k][h]; k<4 -> W1, k==4 -> b1 (bias fold)
        #pragma unroll
        for (int m = 0; m < 4; ++m) {
            BF8 tt;
            #pragma unroll
            for (int j = 0; j < 8; ++j) {
                const int k = g * 8 + j;
                float v = 0.0f;
                if (k < 4) v = W1[k * HH + m * 16 + q];
                else if (k == 4) v = b1[m * 16 + q];
                tt.h[j] = (__bf16)(K2C * v);
            }
            o[m] = tt.u4;
        }
    } else if (w == 1 || w == 2) {
        // L2: A'[row=h2][k] = -2*K2 * W2[hsel(k)][h2]  (consumes r1, not h1)
        const int s = w - 1;
        #pragma unroll
        for (int m = 0; m < 4; ++m) {
            BF8 tt;
            #pragma unroll
            for (int j = 0; j < 8; ++j)
                tt.h[j] = (__bf16)(-2.0f * K2C * W2[hsel(s * 32 + g * 8 + j) * HH + m * 16 + q]);
            o[4 + s * 4 + m] = tt.u4;
        }
    } else {
        // L3: A'[row=o][k] = -2 * W3[hsel(k)][o], rows 3..15 zero
        #pragma unroll
        for (int s = 0; s < 2; ++s) {
            BF8 tt;
            #pragma unroll
            for (int j = 0; j < 8; ++j)
                tt.h[j] = (q < NO) ? (__bf16)(-2.0f * W3[hsel(s * 32 + g * 8 + j) * NO + q])
                                   : (__bf16)0.0f;
            o[12 + s] = tt.u4;
        }
        // Ci2' = K2 * (b2 + colsum(W2)) at C rows m*16 + g*4 + r
        #pragma unroll
        for (int m = 0; m < 4; ++m) {
            F4U tt;
            #pragma unroll
            for (int r = 0; r < 4; ++r) {
                const int idx = m * 16 + g * 4 + r;
                const float cs = cs2p[0][idx] + cs2p[1][idx] + cs2p[2][idx] + cs2p[3][idx];
                tt.f[r] = K2C * (b2[idx] + cs);
            }
            o[14 + m] = tt.u;
        }
        // b3' = b3 + colsum(W3), one shared uint4 slot
        if (l == 0) {
            F4U tt;
            #pragma unroll
            for (int c = 0; c < 3; ++c)
                tt.f[c] = b3[c] + cs3p[0][c] + cs3p[1][c] + cs3p[2][c] + cs3p[3][c];
            tt.f[3] = 0.0f;
            fr[NFRAG * 64] = tt.u;
        }
    }
}

__global__ __launch_bounds__(256) void cppn_main(
    const float* __restrict__ x,
    const uint4* __restrict__ fr,
    float* __restrict__ out,
    float* __restrict__ pmin, float* __restrict__ pmax)
{
    __shared__ float rmin[4], rmax[4];

    const int t = threadIdx.x;
    const int w = t >> 6;
    const int l = t & 63;
    const int g = l >> 4;
    const int q = l & 15;

    // ---- load prebuilt fragments (19 dwordx4, L2-hit) ----
    const uint4* fo = fr + l * NFRAG;
    bf16x8 A1[4], A2[2][4], A3[2];
    #pragma unroll
    for (int m = 0; m < 4; ++m) { BF8 u; u.u4 = fo[m]; A1[m] = u.v; }
    #pragma unroll
    for (int s = 0; s < 2; ++s)
        #pragma unroll
        for (int m = 0; m < 4; ++m) { BF8 u; u.u4 = fo[4 + s * 4 + m]; A2[s][m] = u.v; }
    #pragma unroll
    for (int s = 0; s < 2; ++s) { BF8 u; u.u4 = fo[12 + s]; A3[s] = u.v; }
    f32x4 Ci2[4];
    #pragma unroll
    for (int m = 0; m < 4; ++m) { F4U u; u.u = fo[14 + m]; Ci2[m] = u.v; }
    F4U b3u; b3u.u = fr[NFRAG * 64];
    const float b30 = b3u.f[0], b31 = b3u.f[1], b32 = b3u.f[2];

    const f32x4 z = {0.0f, 0.0f, 0.0f, 0.0f};
    float vmin = INFINITY, vmax = -INFINITY;

    const int pbase = ((blockIdx.x * 4 + w) * ITER) * 16 + q;  // pixel index, it steps +16
    const float4* x4 = reinterpret_cast<const float4*>(x);
    float4 cur = x4[pbase];

    #pragma unroll 2
    for (int it = 0; it < ITER; ++it) {
        // prefetch next iteration's x before the long compute body
        const int itn = (it + 1 < ITER) ? it + 1 : it;
        const float4 nxt = x4[pbase + itn * 16];

        // B1 frag: xaug^T[k][px]; only g==0 lanes carry {x0..x3, 1}
        BF8 bx;
        bx.u4 = uint4{0, 0, 0, 0};
        if (g == 0) {
            PK2 p01, p23;
            p01.h = bf16x2{(__bf16)cur.x, (__bf16)cur.y};
            p23.h = bf16x2{(__bf16)cur.z, (__bf16)cur.w};
            bx.u4.x = p01.u;
            bx.u4.y = p23.u;
            bx.u4.z = 0x3F80u;  // {1.0bf16, 0} bias lane k=4
        }

        // ---- layer 1 (A1 pre-scaled by K2, bias k-augmented) ----
        f32x4 c1[4];
        #pragma unroll
        for (int m = 0; m < 4; ++m) c1[m] = MFMA16(A1[m], bx.v, z);

        unsigned pkx[4], pky[4];
        #pragma unroll
        for (int m = 0; m < 4; ++m) rcp4_pack(c1[m], &pkx[m], &pky[m]);
        BF8 Bf0, Bf1;
        Bf0.u4 = uint4{pkx[0], pky[0], pkx[1], pky[1]};
        Bf1.u4 = uint4{pkx[2], pky[2], pkx[3], pky[3]};

        // ---- layer 2 (A2' = -2*K2*W2 consumes r1; bias' via C-init) ----
        f32x4 c2[4];
        #pragma unroll
        for (int m = 0; m < 4; ++m) {
            c2[m] = MFMA16(A2[0][m], Bf0.v, Ci2[m]);
            c2[m] = MFMA16(A2[1][m], Bf1.v, c2[m]);
        }
        #pragma unroll
        for (int m = 0; m < 4; ++m) rcp4_pack(c2[m], &pkx[m], &pky[m]);
        BF8 Bg0, Bg1;
        Bg0.u4 = uint4{pkx[0], pky[0], pkx[1], pky[1]};
        Bg1.u4 = uint4{pkx[2], pky[2], pkx[3], pky[3]};

        // ---- layer 3 (A3' = -2*W3 consumes r2; bias' scalar add) ----
        f32x4 c3 = MFMA16(A3[0], Bg0.v, z);
        c3 = MFMA16(A3[1], Bg1.v, c3);

        if (g == 0) {
            const int pxg = pbase + it * 16;
            const float o0 = c3[0] + b30;
            const float o1 = c3[1] + b31;
            const float o2 = c3[2] + b32;
            out[0 * NPIX + pxg] = o0;
            out[1 * NPIX + pxg] = o1;
            out[2 * NPIX + pxg] = o2;
            vmin = fminf(vmin, fminf(fminf(o0, o1), o2));
            vmax = fmaxf(vmax, fmaxf(fmaxf(o0, o1), o2));
        }
        cur = nxt;
    }

    // per-block min/max -> partials (no global atomics)
    #pragma unroll
    for (int off = 32; off > 0; off >>= 1) {
        vmin = fminf(vmin, __shfl_down(vmin, off));
        vmax = fmaxf(vmax, __shfl_down(vmax, off));
    }
    if (l == 0) { rmin[w] = vmin; rmax[w] = vmax; }
    __syncthreads();
    if (t == 0) {
        pmin[blockIdx.x] = fminf(fminf(rmin[0], rmin[1]), fminf(rmin[2], rmin[3]));
        pmax[blockIdx.x] = fmaxf(fmaxf(rmax[0], rmax[1]), fmaxf(rmax[2], rmax[3]));
    }
}

// fused reduce+norm: each block redundantly folds the 2048 partials (L2-hit),
// then normalizes its own float4 slice. Exact (min/max order-independent).
__global__ __launch_bounds__(256) void cppn_normred(
    float4* __restrict__ out,
    const float* __restrict__ pmin, const float* __restrict__ pmax)
{
    __shared__ float rmin[4], rmax[4];
    const int t = threadIdx.x, w = t >> 6, l = t & 63;
    float mn = INFINITY, mx = -INFINITY;
    #pragma unroll
    for (int i = 0; i < NBLK / 256; ++i) {
        mn = fminf(mn, pmin[i * 256 + t]);
        mx = fmaxf(mx, pmax[i * 256 + t]);
    }
    #pragma unroll
    for (int off = 32; off > 0; off >>= 1) {
        mn = fminf(mn, __shfl_down(mn, off));
        mx = fmaxf(mx, __shfl_down(mx, off));
    }
    if (l == 0) { rmin[w] = mn; rmax[w] = mx; }
    __syncthreads();
    mn = fminf(fminf(rmin[0], rmin[1]), fminf(rmin[2], rmin[3]));
    mx = fmaxf(fmaxf(rmax[0], rmax[1]), fmaxf(rmax[2], rmax[3]));
    const float inv = __fdividef(1.0f, mx - mn);

    const int i = blockIdx.x * 256 + t;
    float4 v = out[i];
    v.x = fminf(fmaxf((v.x - mn) * inv, 0.0f), 1.0f);
    v.y = fminf(fmaxf((v.y - mn) * inv, 0.0f), 1.0f);
    v.z = fminf(fmaxf((v.z - mn) * inv, 0.0f), 1.0f);
    v.w = fminf(fmaxf((v.w - mn) * inv, 0.0f), 1.0f);
    out[i] = v;
}

extern "C" void kernel_launch(void* const* d_in, const int* in_sizes, int n_in,
                              void* d_out, int out_size, void* d_ws, size_t ws_size,
                              hipStream_t stream) {
    const float* x  = (const float*)d_in[0];
    const float* W1 = (const float*)d_in[1];
    const float* b1 = (const float*)d_in[2];
    const float* W2 = (const float*)d_in[3];
    const float* b2 = (const float*)d_in[4];
    const float* W3 = (const float*)d_in[5];
    const float* b3 = (const float*)d_in[6];
    float* out = (float*)d_out;

    float* pmin = (float*)((char*)d_ws + 1024);          // 2048 floats
    float* pmax = (float*)((char*)d_ws + 1024 + 8192);   // 2048 floats
    uint4* fr   = (uint4*)((char*)d_ws + 32768);         // 64*18+1 uint4 ≈ 18 KB

    cppn_pack<<<1, 256, 0, stream>>>(W1, b1, W2, b2, W3, b3, fr);
    cppn_main<<<NBLK, 256, 0, stream>>>(x, fr, out, pmin, pmax);
    cppn_normred<<<NOUT4 / 256, 256, 0, stream>>>((float4*)out, pmin, pmax);
}